// Round 4
// baseline (217.236 us; speedup 1.0000x reference)
//
#include <hip/hip_runtime.h>
#include <stdint.h>

#define KSTEPS 24              // 768 / 32
#define TOKENS 16384           // B*S

typedef short short8 __attribute__((ext_vector_type(8)));
typedef float fx4 __attribute__((ext_vector_type(4)));
typedef unsigned short u16;
typedef u16 u16x4 __attribute__((ext_vector_type(4)));

static __device__ __forceinline__ u16 f2bf(float f) {
  union { float f; unsigned u; } v; v.f = f;
  return (u16)((v.u + 0x7fffu + ((v.u >> 16) & 1u)) >> 16);
}

static __device__ __forceinline__ fx4 mfma16(short8 a, short8 b, fx4 c) {
  return __builtin_amdgcn_mfma_f32_16x16x32_bf16(a, b, c, 0, 0, 0);
}

// async global->LDS, 16B/lane; lds dest = wave-uniform base + lane*16
static __device__ __forceinline__ void async16(const void* g, void* l) {
  __builtin_amdgcn_global_load_lds(
      (const __attribute__((address_space(1))) void*)g,
      (__attribute__((address_space(3))) void*)(unsigned int)(uintptr_t)l,
      16, 0, 0);
}

// ---------------- prep: W[768][64] fp32 (q,k,v) -> bf16 pre-fragmented B-operand layout
__global__ void prep_w_kernel(const float* __restrict__ Wq, const float* __restrict__ Wk,
                              const float* __restrict__ Wv, u16* __restrict__ wfrag) {
  int idx  = blockIdx.x * 256 + threadIdx.x;   // 72*256 = 18432 = 3*24*4*64
  int lane = idx & 63;
  int fid  = idx >> 6;
  int nt   = fid & 3;
  int ks   = (fid >> 2) % KSTEPS;
  int mat  = fid / (KSTEPS * 4);
  const float* W = (mat == 0) ? Wq : (mat == 1) ? Wk : Wv;
  int n  = nt * 16 + (lane & 15);
  int k0 = ks * 32 + (lane >> 4) * 8;
  short8 out;
#pragma unroll
  for (int j = 0; j < 8; j++) out[j] = (short)f2bf(W[(size_t)(k0 + j) * 64 + n]);
  *(short8*)(wfrag + (size_t)idx * 8) = out;
}

// ---------------- projection GEMM: 32 tok/block, 256 thr, W+x staged in LDS, dbuf
__global__ __launch_bounds__(256) void proj_kernel(const float* __restrict__ x,
                                                   const u16* __restrict__ wfrag,
                                                   u16* __restrict__ qb,
                                                   u16* __restrict__ kb,
                                                   u16* __restrict__ vT) {
  __shared__ float xs[2][32 * 32];    // [dbuf][tok][32 floats] chunk-swizzled
  __shared__ u16  Ws[2][12 * 512];    // [dbuf][f=(m*4+nt)][lane][8]

  int w = threadIdx.x >> 6, lane = threadIdx.x & 63;
  int ln = lane & 15, quad = lane >> 4;
  int rw = w >> 1, cs = w & 1;
  int s0 = blockIdx.x * 32;

  fx4 acc[6];
#pragma unroll
  for (int j = 0; j < 6; j++) acc[j] = (fx4){0.f, 0.f, 0.f, 0.f};

  int srow  = w * 8 + (lane >> 3);
  int slot  = lane & 7;
  int chunk = slot ^ (srow & 7);
  const float* xsrc = x + (size_t)(s0 + srow) * 768 + chunk * 4;

#pragma unroll
  for (int m = 0; m < 3; m++)
    async16(wfrag + ((size_t)(m * KSTEPS + 0) * 256 + w * 64 + lane) * 8,
            (char*)Ws[0] + m * 4096 + w * 1024 + lane * 16);
  async16(xsrc, (char*)xs[0] + w * 1024 + lane * 16);

  int r = rw * 16 + ln;
  for (int ks = 0; ks < KSTEPS; ks++) {
    __syncthreads();
    if (ks < KSTEPS - 1) {
      int buf = (ks + 1) & 1;
#pragma unroll
      for (int m = 0; m < 3; m++)
        async16(wfrag + ((size_t)(m * KSTEPS + ks + 1) * 256 + w * 64 + lane) * 8,
                (char*)Ws[buf] + m * 4096 + w * 1024 + lane * 16);
      async16(xsrc + (ks + 1) * 32, (char*)xs[buf] + w * 1024 + lane * 16);
    }
    const float* xb = xs[ks & 1];
    const u16*  wb = Ws[ks & 1];
    int sl0 = (2 * quad)     ^ (r & 7);
    int sl1 = (2 * quad + 1) ^ (r & 7);
    fx4 xa = *(const fx4*)(xb + r * 32 + sl0 * 4);
    fx4 xv = *(const fx4*)(xb + r * 32 + sl1 * 4);
    short8 af;
#pragma unroll
    for (int j = 0; j < 4; j++) { af[j] = (short)f2bf(xa[j]); af[4 + j] = (short)f2bf(xv[j]); }
#pragma unroll
    for (int j = 0; j < 6; j++) {
      short8 bf = *(const short8*)(wb + (cs * 6 + j) * 512 + lane * 8);
      acc[j] = mfma16(af, bf, acc[j]);
    }
  }

  int tok0 = s0 + rw * 16 + quad * 4;
#pragma unroll
  for (int j = 0; j < 6; j++) {
    int f = cs * 6 + j;
    int d = (f & 3) * 16 + ln;
    if (f < 4) {
      // Q pre-scaled by 0.125 * log2(e): scores land in exp2 domain
#pragma unroll
      for (int reg = 0; reg < 4; reg++)
        qb[(size_t)(tok0 + reg) * 64 + d] = f2bf(acc[j][reg] * 0.180336887f);
    } else if (f < 8) {
#pragma unroll
      for (int reg = 0; reg < 4; reg++)
        kb[(size_t)(tok0 + reg) * 64 + d] = f2bf(acc[j][reg]);
    } else {
      int b = tok0 >> 12, s = tok0 & 4095;
      u16x4 vp;
#pragma unroll
      for (int reg = 0; reg < 4; reg++) vp[reg] = f2bf(acc[j][reg]);
      *(u16x4*)(vT + ((size_t)b * 64 + d) * 4096 + s) = vp;
    }
  }
}

// ---------------- flash attention: no K-loop barriers, direct-global B-frags
// 4 waves = 2 row-waves (rw) x 2 kt-groups (g); merge partials at the end
__global__ __launch_bounds__(256) void attn_kernel(const u16* __restrict__ qb,
                                                   const u16* __restrict__ kb,
                                                   const u16* __restrict__ vT,
                                                   float* __restrict__ out) {
  __shared__ u16 Ps[4][16 * 72];      // per-wave P round-trip, padded rows
  __shared__ float cmb[2240];         // merge: o[2][16][68] + m[32] + l[32]

  int b = blockIdx.y;
  int qt = 127 - blockIdx.x;          // big blocks first
  int w = threadIdx.x >> 6, lane = threadIdx.x & 63;
  int g = w >> 1, rw = w & 1;
  int ln = lane & 15, quad = lane >> 4;
  int q0 = qt * 32;

  const u16* qbb = qb + (size_t)b * 4096 * 64;
  const u16* kbb = kb + (size_t)b * 4096 * 64;
  const u16* vtb = vT + (size_t)b * 64 * 4096;
  float* outb = out + (size_t)b * 4096 * 64;

  short8 qf0 = *(const short8*)(qbb + (size_t)(q0 + rw * 16 + ln) * 64 + quad * 8);
  short8 qf1 = *(const short8*)(qbb + (size_t)(q0 + rw * 16 + ln) * 64 + 32 + quad * 8);

  short8 ones;
#pragma unroll
  for (int j = 0; j < 8; j++) ones[j] = (short)0x3F80;   // bf16 1.0

  fx4 o[4];
#pragma unroll
  for (int nt2 = 0; nt2 < 4; nt2++) o[nt2] = (fx4){0.f, 0.f, 0.f, 0.f};
  float m_i[4] = {-1e30f, -1e30f, -1e30f, -1e30f};
  float l_i[4] = {0.f, 0.f, 0.f, 0.f};

  int n = (qt + 2) >> 1;              // 64-key tiles this q-block needs

  // K B-frag: lane ln -> key, quad -> d-chunk; 16B contiguous in kb[tok][64]
  const u16* kfp = kbb + (size_t)(ln)*64 + quad * 8;
  // V B-frag: lane ln -> d, quad -> key-chunk; 16B contiguous in vT[d][4096]
  const u16* vfp = vtb + (size_t)(ln)*4096 + quad * 8;

  short8 kc[8];
  if (g < n) {
#pragma unroll
    for (int nt = 0; nt < 4; nt++) {
      kc[nt * 2]     = *(const short8*)(kfp + (size_t)(g * 64 + nt * 16) * 64);
      kc[nt * 2 + 1] = *(const short8*)(kfp + (size_t)(g * 64 + nt * 16) * 64 + 32);
    }
  }

  for (int t = g; t < n; t += 2) {
    // V frags for this tile (latency covered by QK + softmax below)
    short8 vf[8];
#pragma unroll
    for (int nt2 = 0; nt2 < 4; nt2++) {
      vf[nt2 * 2]     = *(const short8*)(vfp + (size_t)(nt2 * 16) * 4096 + t * 64);
      vf[nt2 * 2 + 1] = *(const short8*)(vfp + (size_t)(nt2 * 16) * 4096 + t * 64 + 32);
    }
    // K frags for the next tile (full tile of latency cover)
    short8 kn[8];
    if (t + 2 < n) {
#pragma unroll
      for (int nt = 0; nt < 4; nt++) {
        kn[nt * 2]     = *(const short8*)(kfp + (size_t)((t + 2) * 64 + nt * 16) * 64);
        kn[nt * 2 + 1] = *(const short8*)(kfp + (size_t)((t + 2) * 64 + nt * 16) * 64 + 32);
      }
    }

    // S = Q K^T (already in exp2 domain)
    fx4 sA[4];
#pragma unroll
    for (int nt = 0; nt < 4; nt++) {
      sA[nt] = mfma16(qf0, kc[nt * 2], (fx4){0.f, 0.f, 0.f, 0.f});
      sA[nt] = mfma16(qf1, kc[nt * 2 + 1], sA[nt]);
    }

    if (t == n - 1) {  // diagonal tile mask
#pragma unroll
      for (int nt = 0; nt < 4; nt++)
#pragma unroll
        for (int reg = 0; reg < 4; reg++) {
          int col = t * 64 + nt * 16 + ln;
          int rowg = q0 + rw * 16 + quad * 4 + reg;
          if (col > rowg) sA[nt][reg] = -1e30f;
        }
    }

    // online softmax (log2 domain): running max via 16-lane shuffles
    float alpha[4];
#pragma unroll
    for (int reg = 0; reg < 4; reg++) {
      float v = fmaxf(fmaxf(sA[0][reg], sA[1][reg]), fmaxf(sA[2][reg], sA[3][reg]));
#pragma unroll
      for (int off = 1; off < 16; off <<= 1) v = fmaxf(v, __shfl_xor(v, off));
      float mn = fmaxf(m_i[reg], v);
      alpha[reg] = __builtin_amdgcn_exp2f(m_i[reg] - mn);
      m_i[reg] = mn;
    }
    // p = 2^(s - m), straight into the LDS round-trip buffer
#pragma unroll
    for (int nt = 0; nt < 4; nt++)
#pragma unroll
      for (int reg = 0; reg < 4; reg++)
        Ps[w][(quad * 4 + reg) * 72 + nt * 16 + ln] =
            f2bf(__builtin_amdgcn_exp2f(sA[nt][reg] - m_i[reg]));

    short8 pf0 = *(const short8*)(&Ps[w][ln * 72 + quad * 8]);
    short8 pf1 = *(const short8*)(&Ps[w][ln * 72 + 32 + quad * 8]);

    // row-sum of P via MFMA with ones-B (replaces shuffle-add reduction)
    fx4 lacc = mfma16(pf0, ones, (fx4){0.f, 0.f, 0.f, 0.f});
    lacc = mfma16(pf1, ones, lacc);
#pragma unroll
    for (int reg = 0; reg < 4; reg++) l_i[reg] = l_i[reg] * alpha[reg] + lacc[reg];

#pragma unroll
    for (int nt2 = 0; nt2 < 4; nt2++)
#pragma unroll
      for (int reg = 0; reg < 4; reg++) o[nt2][reg] *= alpha[reg];

#pragma unroll
    for (int nt2 = 0; nt2 < 4; nt2++) {
      o[nt2] = mfma16(pf0, vf[nt2 * 2], o[nt2]);
      o[nt2] = mfma16(pf1, vf[nt2 * 2 + 1], o[nt2]);
    }

#pragma unroll
    for (int j = 0; j < 8; j++) kc[j] = kn[j];
  }

  // merge the two kt-groups' partials (log2-domain m)
  __syncthreads();
  if (g == 1) {
#pragma unroll
    for (int nt2 = 0; nt2 < 4; nt2++)
#pragma unroll
      for (int reg = 0; reg < 4; reg++)
        cmb[rw * 1088 + (quad * 4 + reg) * 68 + nt2 * 16 + ln] = o[nt2][reg];
    if (ln == 0) {
#pragma unroll
      for (int reg = 0; reg < 4; reg++) {
        cmb[2176 + rw * 16 + quad * 4 + reg] = m_i[reg];
        cmb[2208 + rw * 16 + quad * 4 + reg] = l_i[reg];
      }
    }
  }
  __syncthreads();
  if (g == 0) {
    float a0[4], a1[4], inv[4];
#pragma unroll
    for (int reg = 0; reg < 4; reg++) {
      float m1 = cmb[2176 + rw * 16 + quad * 4 + reg];
      float l1 = cmb[2208 + rw * 16 + quad * 4 + reg];
      float mf = fmaxf(m_i[reg], m1);
      a0[reg] = __builtin_amdgcn_exp2f(m_i[reg] - mf);
      a1[reg] = __builtin_amdgcn_exp2f(m1 - mf);
      inv[reg] = 1.0f / (l_i[reg] * a0[reg] + l1 * a1[reg]);
    }
#pragma unroll
    for (int nt2 = 0; nt2 < 4; nt2++)
#pragma unroll
      for (int reg = 0; reg < 4; reg++) {
        float o1 = cmb[rw * 1088 + (quad * 4 + reg) * 68 + nt2 * 16 + ln];
        int rowg = q0 + rw * 16 + quad * 4 + reg;
        outb[(size_t)rowg * 64 + nt2 * 16 + ln] =
            (o[nt2][reg] * a0[reg] + o1 * a1[reg]) * inv[reg];
      }
  }
}

extern "C" void kernel_launch(void* const* d_in, const int* in_sizes, int n_in,
                              void* d_out, int out_size, void* d_ws, size_t ws_size,
                              hipStream_t stream) {
  const float* x  = (const float*)d_in[0];
  const float* Wq = (const float*)d_in[1];
  const float* Wk = (const float*)d_in[2];
  const float* Wv = (const float*)d_in[3];

  u16* qbw = (u16*)d_ws;                          // [16384][64] bf16
  u16* kbw = qbw + (size_t)TOKENS * 64;           // [16384][64] bf16
  u16* vtw = kbw + (size_t)TOKENS * 64;           // [4][64][4096] bf16
  u16* wfr = vtw + (size_t)TOKENS * 64;           // [3][24][4][64][8] bf16

  prep_w_kernel<<<72, 256, 0, stream>>>(Wq, Wk, Wv, wfr);
  proj_kernel<<<TOKENS / 32, 256, 0, stream>>>(x, wfr, qbw, kbw, vtw);
  attn_kernel<<<dim3(128, 4), 256, 0, stream>>>(qbw, kbw, vtw, (float*)d_out);
}

// Round 5
// 166.149 us; speedup vs baseline: 1.3075x; 1.3075x over previous
//
#include <hip/hip_runtime.h>
#include <stdint.h>

#define KSTEPS 24              // 768 / 32
#define TOKENS 16384           // B*S

typedef short short8 __attribute__((ext_vector_type(8)));
typedef float fx4 __attribute__((ext_vector_type(4)));
typedef unsigned short u16;
typedef u16 u16x4 __attribute__((ext_vector_type(4)));

static __device__ __forceinline__ u16 f2bf(float f) {
  union { float f; unsigned u; } v; v.f = f;
  return (u16)((v.u + 0x7fffu + ((v.u >> 16) & 1u)) >> 16);
}

static __device__ __forceinline__ fx4 mfma16(short8 a, short8 b, fx4 c) {
  return __builtin_amdgcn_mfma_f32_16x16x32_bf16(a, b, c, 0, 0, 0);
}

// async global->LDS, 16B/lane; lds dest = wave-uniform base + lane*16
static __device__ __forceinline__ void async16(const void* g, void* l) {
  __builtin_amdgcn_global_load_lds(
      (const __attribute__((address_space(1))) void*)g,
      (__attribute__((address_space(3))) void*)(unsigned int)(uintptr_t)l,
      16, 0, 0);
}

// ---------------- prep: W[768][64] fp32 (q,k,v) -> bf16 pre-fragmented B-operand layout
__global__ void prep_w_kernel(const float* __restrict__ Wq, const float* __restrict__ Wk,
                              const float* __restrict__ Wv, u16* __restrict__ wfrag) {
  int idx  = blockIdx.x * 256 + threadIdx.x;   // 72*256 = 18432 = 3*24*4*64
  int lane = idx & 63;
  int fid  = idx >> 6;
  int nt   = fid & 3;
  int ks   = (fid >> 2) % KSTEPS;
  int mat  = fid / (KSTEPS * 4);
  const float* W = (mat == 0) ? Wq : (mat == 1) ? Wk : Wv;
  int n  = nt * 16 + (lane & 15);
  int k0 = ks * 32 + (lane >> 4) * 8;
  short8 out;
#pragma unroll
  for (int j = 0; j < 8; j++) out[j] = (short)f2bf(W[(size_t)(k0 + j) * 64 + n]);
  *(short8*)(wfrag + (size_t)idx * 8) = out;
}

// ---------------- projection GEMM: 32 tok/block, 256 thr, W+x staged in LDS, dbuf
__global__ __launch_bounds__(256) void proj_kernel(const float* __restrict__ x,
                                                   const u16* __restrict__ wfrag,
                                                   u16* __restrict__ qb,
                                                   u16* __restrict__ kb,
                                                   u16* __restrict__ vT) {
  __shared__ float xs[2][32 * 32];    // [dbuf][tok][32 floats] chunk-swizzled
  __shared__ u16  Ws[2][12 * 512];    // [dbuf][f=(m*4+nt)][lane][8]

  int w = threadIdx.x >> 6, lane = threadIdx.x & 63;
  int ln = lane & 15, quad = lane >> 4;
  int rw = w >> 1, cs = w & 1;
  int s0 = blockIdx.x * 32;

  fx4 acc[6];
#pragma unroll
  for (int j = 0; j < 6; j++) acc[j] = (fx4){0.f, 0.f, 0.f, 0.f};

  int srow  = w * 8 + (lane >> 3);
  int slot  = lane & 7;
  int chunk = slot ^ (srow & 7);
  const float* xsrc = x + (size_t)(s0 + srow) * 768 + chunk * 4;

#pragma unroll
  for (int m = 0; m < 3; m++)
    async16(wfrag + ((size_t)(m * KSTEPS + 0) * 256 + w * 64 + lane) * 8,
            (char*)Ws[0] + m * 4096 + w * 1024 + lane * 16);
  async16(xsrc, (char*)xs[0] + w * 1024 + lane * 16);

  int r = rw * 16 + ln;
  for (int ks = 0; ks < KSTEPS; ks++) {
    __syncthreads();
    if (ks < KSTEPS - 1) {
      int buf = (ks + 1) & 1;
#pragma unroll
      for (int m = 0; m < 3; m++)
        async16(wfrag + ((size_t)(m * KSTEPS + ks + 1) * 256 + w * 64 + lane) * 8,
                (char*)Ws[buf] + m * 4096 + w * 1024 + lane * 16);
      async16(xsrc + (ks + 1) * 32, (char*)xs[buf] + w * 1024 + lane * 16);
    }
    const float* xb = xs[ks & 1];
    const u16*  wb = Ws[ks & 1];
    int sl0 = (2 * quad)     ^ (r & 7);
    int sl1 = (2 * quad + 1) ^ (r & 7);
    fx4 xa = *(const fx4*)(xb + r * 32 + sl0 * 4);
    fx4 xv = *(const fx4*)(xb + r * 32 + sl1 * 4);
    short8 af;
#pragma unroll
    for (int j = 0; j < 4; j++) { af[j] = (short)f2bf(xa[j]); af[4 + j] = (short)f2bf(xv[j]); }
#pragma unroll
    for (int j = 0; j < 6; j++) {
      short8 bf = *(const short8*)(wb + (cs * 6 + j) * 512 + lane * 8);
      acc[j] = mfma16(af, bf, acc[j]);
    }
  }

  int tok0 = s0 + rw * 16 + quad * 4;
#pragma unroll
  for (int j = 0; j < 6; j++) {
    int f = cs * 6 + j;
    int d = (f & 3) * 16 + ln;
    if (f < 4) {
      // Q pre-scaled by 0.125 * log2(e): scores land in exp2 domain
#pragma unroll
      for (int reg = 0; reg < 4; reg++)
        qb[(size_t)(tok0 + reg) * 64 + d] = f2bf(acc[j][reg] * 0.180336887f);
    } else if (f < 8) {
#pragma unroll
      for (int reg = 0; reg < 4; reg++)
        kb[(size_t)(tok0 + reg) * 64 + d] = f2bf(acc[j][reg]);
    } else {
      int b = tok0 >> 12, s = tok0 & 4095;
      u16x4 vp;
#pragma unroll
      for (int reg = 0; reg < 4; reg++) vp[reg] = f2bf(acc[j][reg]);
      *(u16x4*)(vT + ((size_t)b * 64 + d) * 4096 + s) = vp;
    }
  }
}

// stage one 64-key K tile (8KB), chunk-swizzled source, this wave does half
static __device__ __forceinline__ void stage_k(const u16* kbb, u16* kdst,
                                               int t, int rw, int lane) {
  int l3 = lane >> 3, slot = lane & 7;
#pragma unroll
  for (int c = 0; c < 4; c++) {
    int row = rw * 32 + c * 8 + l3;
    int ch = slot ^ (row & 7);
    async16(kbb + ((size_t)t * 64 + row) * 64 + ch * 8, (char*)kdst + rw * 4096 + c * 1024);
  }
}

// ---------------- flash attention, split-K across blocks (z=0/1), BM=32
// 4 waves = 2 row-waves (rw) x 2 kt-groups (g); K LDS-staged dbuf, V direct-to-reg
__global__ __launch_bounds__(256) void attn_kernel(const u16* __restrict__ qb,
                                                   const u16* __restrict__ kb,
                                                   const u16* __restrict__ vT,
                                                   float* __restrict__ o0g,
                                                   float* __restrict__ po1,
                                                   float* __restrict__ mlb) {
  __shared__ u16 Kstg[2][2][4096];    // [g][buf][64 keys * 64 d] = 32KB
  __shared__ u16 Ps[4][16 * 72];      // per-wave P round-trip, padded rows
  __shared__ float cmb[2240];         // g-merge: o[2][16][68] + m[32] + l[32]

  int b = blockIdx.y, z = blockIdx.z;
  int qt = 127 - blockIdx.x;          // big blocks first
  int w = threadIdx.x >> 6, lane = threadIdx.x & 63;
  int g = w >> 1, rw = w & 1;
  int ln = lane & 15, quad = lane >> 4;
  int q0 = qt * 32;

  const u16* qbb = qb + (size_t)b * 4096 * 64;
  const u16* kbb = kb + (size_t)b * 4096 * 64;
  const u16* vtb = vT + (size_t)b * 64 * 4096;

  short8 qf0 = *(const short8*)(qbb + (size_t)(q0 + rw * 16 + ln) * 64 + quad * 8);
  short8 qf1 = *(const short8*)(qbb + (size_t)(q0 + rw * 16 + ln) * 64 + 32 + quad * 8);

  short8 ones;
#pragma unroll
  for (int j = 0; j < 8; j++) ones[j] = (short)0x3F80;   // bf16 1.0

  fx4 o[4];
#pragma unroll
  for (int nt2 = 0; nt2 < 4; nt2++) o[nt2] = (fx4){0.f, 0.f, 0.f, 0.f};
  float m_i[4] = {-1e30f, -1e30f, -1e30f, -1e30f};
  float l_i[4] = {0.f, 0.f, 0.f, 0.f};

  int n = (qt + 2) >> 1;              // 64-key tiles for this q-block
  int h = (n + 1) >> 1;               // split point
  int lo = z ? h : 0, hi = z ? n : h;
  int L = hi - lo, R = (L + 1) >> 1;  // rounds per kt-group (unified)

  // V B-frag base: lane ln -> d, quad -> key-chunk; 16B contiguous in vT[d][4096]
  const u16* vfp = vtb + (size_t)ln * 4096 + quad * 8;

  if (g < L) stage_k(kbb, Kstg[g][0], lo + g, rw, lane);

  for (int rr = 0; rr < R; rr++) {
    __syncthreads();                  // publishes buf rr&1 (drains all DMA)
    int t = lo + 2 * rr + g;
    // V frags for this tile FIRST (oldest in vmcnt FIFO -> PV wait doesn't drain DMA)
    short8 vf[8];
    if (t < hi) {
#pragma unroll
      for (int nt2 = 0; nt2 < 4; nt2++) {
        vf[nt2 * 2]     = *(const short8*)(vfp + (size_t)(nt2 * 16) * 4096 + t * 64);
        vf[nt2 * 2 + 1] = *(const short8*)(vfp + (size_t)(nt2 * 16) * 4096 + t * 64 + 32);
      }
    }
    int tn = t + 2;
    if (tn < hi) stage_k(kbb, Kstg[g][(rr + 1) & 1], tn, rw, lane);
    if (t < hi) {
      const u16* Kb = Kstg[g][rr & 1];
      // S = Q K^T (already in exp2 domain)
      fx4 sA[4];
#pragma unroll
      for (int nt = 0; nt < 4; nt++) {
        int row = nt * 16 + ln;
        int s0_ = quad ^ (row & 7), s1_ = (quad + 4) ^ (row & 7);
        short8 kf0 = *(const short8*)(Kb + row * 64 + s0_ * 8);
        short8 kf1 = *(const short8*)(Kb + row * 64 + s1_ * 8);
        sA[nt] = mfma16(qf0, kf0, (fx4){0.f, 0.f, 0.f, 0.f});
        sA[nt] = mfma16(qf1, kf1, sA[nt]);
      }
      if (t == n - 1) {  // diagonal tile mask
#pragma unroll
        for (int nt = 0; nt < 4; nt++)
#pragma unroll
          for (int reg = 0; reg < 4; reg++) {
            int col = t * 64 + nt * 16 + ln;
            int rowg = q0 + rw * 16 + quad * 4 + reg;
            if (col > rowg) sA[nt][reg] = -1e30f;
          }
      }
      // online softmax (exp2 domain)
      float alpha[4];
#pragma unroll
      for (int reg = 0; reg < 4; reg++) {
        float v = fmaxf(fmaxf(sA[0][reg], sA[1][reg]), fmaxf(sA[2][reg], sA[3][reg]));
#pragma unroll
        for (int off = 1; off < 16; off <<= 1) v = fmaxf(v, __shfl_xor(v, off));
        float mn = fmaxf(m_i[reg], v);
        alpha[reg] = __builtin_amdgcn_exp2f(m_i[reg] - mn);
        m_i[reg] = mn;
      }
      // p = 2^(s - m) straight into the LDS round-trip buffer
#pragma unroll
      for (int nt = 0; nt < 4; nt++)
#pragma unroll
        for (int reg = 0; reg < 4; reg++)
          Ps[w][(quad * 4 + reg) * 72 + nt * 16 + ln] =
              f2bf(__builtin_amdgcn_exp2f(sA[nt][reg] - m_i[reg]));

      short8 pf0 = *(const short8*)(&Ps[w][ln * 72 + quad * 8]);
      short8 pf1 = *(const short8*)(&Ps[w][ln * 72 + 32 + quad * 8]);

      // row-sum of P via MFMA with ones-B
      fx4 lacc = mfma16(pf0, ones, (fx4){0.f, 0.f, 0.f, 0.f});
      lacc = mfma16(pf1, ones, lacc);
#pragma unroll
      for (int reg = 0; reg < 4; reg++) l_i[reg] = l_i[reg] * alpha[reg] + lacc[reg];

#pragma unroll
      for (int nt2 = 0; nt2 < 4; nt2++)
#pragma unroll
        for (int reg = 0; reg < 4; reg++) o[nt2][reg] *= alpha[reg];

#pragma unroll
      for (int nt2 = 0; nt2 < 4; nt2++) {
        o[nt2] = mfma16(pf0, vf[nt2 * 2], o[nt2]);
        o[nt2] = mfma16(pf1, vf[nt2 * 2 + 1], o[nt2]);
      }
    }
  }

  // merge the two kt-groups' partials; write UNNORMALIZED block partial + (m,l)
  __syncthreads();                    // also drains any straggler DMA before cmb reuse
  if (g == 1) {
#pragma unroll
    for (int nt2 = 0; nt2 < 4; nt2++)
#pragma unroll
      for (int reg = 0; reg < 4; reg++)
        cmb[rw * 1088 + (quad * 4 + reg) * 68 + nt2 * 16 + ln] = o[nt2][reg];
    if (ln == 0) {
#pragma unroll
      for (int reg = 0; reg < 4; reg++) {
        cmb[2176 + rw * 16 + quad * 4 + reg] = m_i[reg];
        cmb[2208 + rw * 16 + quad * 4 + reg] = l_i[reg];
      }
    }
  }
  __syncthreads();
  if (g == 0) {
    float* dst = z ? po1 : o0g;
    float a0[4], a1[4], mf[4], ls[4];
#pragma unroll
    for (int reg = 0; reg < 4; reg++) {
      float m1 = cmb[2176 + rw * 16 + quad * 4 + reg];
      float l1 = cmb[2208 + rw * 16 + quad * 4 + reg];
      mf[reg] = fmaxf(m_i[reg], m1);
      a0[reg] = __builtin_amdgcn_exp2f(m_i[reg] - mf[reg]);
      a1[reg] = __builtin_amdgcn_exp2f(m1 - mf[reg]);
      ls[reg] = l_i[reg] * a0[reg] + l1 * a1[reg];
    }
#pragma unroll
    for (int nt2 = 0; nt2 < 4; nt2++)
#pragma unroll
      for (int reg = 0; reg < 4; reg++) {
        float o1 = cmb[rw * 1088 + (quad * 4 + reg) * 68 + nt2 * 16 + ln];
        int rowg = q0 + rw * 16 + quad * 4 + reg;
        dst[((size_t)b * 4096 + rowg) * 64 + nt2 * 16 + ln] =
            o[nt2][reg] * a0[reg] + o1 * a1[reg];
      }
    if (ln == 0) {
#pragma unroll
      for (int reg = 0; reg < 4; reg++) {
        int rowg = q0 + rw * 16 + quad * 4 + reg;
        float2 v; v.x = mf[reg]; v.y = ls[reg];
        ((float2*)mlb)[((size_t)z * 4 + b) * 4096 + rowg] = v;
      }
    }
  }
}

// ---------------- merge the two split-K halves
__global__ __launch_bounds__(256) void merge_kernel(float* __restrict__ out,
                                                    const float* __restrict__ po1,
                                                    const float* __restrict__ mlb) {
  int qt = blockIdx.x, b = blockIdx.y;
  int r = threadIdx.x >> 3;
  int c = (threadIdx.x & 7) * 8;
  size_t row = (size_t)b * 4096 + qt * 32 + r;
  const float2* ml2 = (const float2*)mlb;
  float2 p0 = ml2[row];
  float2 p1 = ml2[(size_t)4 * 4096 + row];
  float mf = fmaxf(p0.x, p1.x);
  float a0 = __builtin_amdgcn_exp2f(p0.x - mf);
  float a1 = __builtin_amdgcn_exp2f(p1.x - mf);
  float inv = 1.0f / (p0.y * a0 + p1.y * a1);
  float* op = out + row * 64 + c;
  const float* p1p = po1 + row * 64 + c;
  fx4 u0 = *(fx4*)op, u1 = *(fx4*)(op + 4);
  fx4 v0 = *(const fx4*)p1p, v1 = *(const fx4*)(p1p + 4);
#pragma unroll
  for (int j = 0; j < 4; j++) {
    u0[j] = (u0[j] * a0 + v0[j] * a1) * inv;
    u1[j] = (u1[j] * a0 + v1[j] * a1) * inv;
  }
  *(fx4*)op = u0;
  *(fx4*)(op + 4) = u1;
}

extern "C" void kernel_launch(void* const* d_in, const int* in_sizes, int n_in,
                              void* d_out, int out_size, void* d_ws, size_t ws_size,
                              hipStream_t stream) {
  const float* x  = (const float*)d_in[0];
  const float* Wq = (const float*)d_in[1];
  const float* Wk = (const float*)d_in[2];
  const float* Wv = (const float*)d_in[3];

  u16* qbw = (u16*)d_ws;                          // [16384][64] bf16, 2MB
  u16* kbw = qbw + (size_t)TOKENS * 64;           // 2MB
  u16* vtw = kbw + (size_t)TOKENS * 64;           // 2MB
  u16* wfr = vtw + (size_t)TOKENS * 64;           // 288KB
  float* po1 = (float*)(wfr + (size_t)3 * KSTEPS * 256 * 8);  // [4][4096][64] fp32, 4MB
  float* mlb = po1 + (size_t)4 * 4096 * 64;       // [2][4][4096] float2, 256KB

  prep_w_kernel<<<72, 256, 0, stream>>>(Wq, Wk, Wv, wfr);
  proj_kernel<<<TOKENS / 32, 256, 0, stream>>>(x, wfr, qbw, kbw, vtw);
  attn_kernel<<<dim3(128, 4, 2), 256, 0, stream>>>(qbw, kbw, vtw,
                                                   (float*)d_out, po1, mlb);
  merge_kernel<<<dim3(128, 4), 256, 0, stream>>>((float*)d_out, po1, mlb);
}